// Round 1
// 261.658 us; speedup vs baseline: 1.0291x; 1.0291x over previous
//
#include <hip/hip_runtime.h>
#include <stdint.h>

typedef unsigned short u16;
typedef __bf16 bf16x8 __attribute__((ext_vector_type(8)));
typedef float f32x4 __attribute__((ext_vector_type(4)));
typedef float f32x16 __attribute__((ext_vector_type(16)));
typedef unsigned int u32;

// ---------------------------------------------------------------------------
// Weight "A-image" (u16 elems), 32x32x16-MFMA A-frag native granules:
//   elem[((koct*R + row)*8) + (k&7)],  koct = k>>3, R = rows.
//   L0    : kocts 0..13 (K=112: 96 enc + bias@96 + pad), R=128 -> 14336 elems
//   Hidden: kocts 0..29 (K=240: 128 hid + 96 enc + bias@224 + pad), R=128 -> 30720
//   Out   : kocts 0..29, R=32 (4 real rows) -> 7680
// ---------------------------------------------------------------------------
#define IMG_H(l) (14336 + ((l)-1) * 30720)
#define IMG_OUT 229376
#define IMG_TOTAL 237056

// hidden-feature k-position -> producing layer's C/D feature index.
__device__ inline int fmap(int k) {
    int s = k >> 4, h = (k >> 3) & 1, j = k & 7;
    return 32 * (s >> 1) + 16 * (s & 1) + 8 * (j >> 2) + 4 * h + (j & 3);
}
__device__ inline u16 b16rne(float v) {
    u32 u = __builtin_bit_cast(u32, v);
    u += 0x7FFFu + ((u >> 16) & 1u);
    return (u16)(u >> 16);
}

// ---------------------------------------------------------------------------
// Prep kernel: build bf16 A-image (fmap-permuted hidden cols, identity enc
// cols, bias folded at k=96/224, zero padding).
// ---------------------------------------------------------------------------
__global__ void nf_prep(const float* __restrict__ W0, const float* __restrict__ b0,
                        const float* __restrict__ Wh, const float* __restrict__ bh,
                        const float* __restrict__ Wl, const float* __restrict__ bl,
                        u16* __restrict__ img) {
    int idx = blockIdx.x * 256 + threadIdx.x;
    if (idx >= IMG_TOTAL) return;
    float v;
    if (idx < 14336) {                                    // layer 0
        int gg = idx >> 3, j = idx & 7;
        int koct = gg >> 7, i = gg & 127, k = koct * 8 + j;
        v = (k < 96) ? W0[k * 128 + i] : (k == 96) ? b0[i] : 0.f;
    } else if (idx < IMG_OUT) {                           // hidden 1..7
        int r = idx - 14336, l = r / 30720, rr = r % 30720;
        int gg = rr >> 3, j = rr & 7;
        int koct = gg >> 7, i = gg & 127, k = koct * 8 + j;
        const float* W = Wh + l * 224 * 128;
        v = (k < 128) ? W[fmap(k) * 128 + i]
          : (k < 224) ? W[k * 128 + i]
          : (k == 224) ? bh[l * 128 + i] : 0.f;
    } else {                                              // output layer
        int r = idx - IMG_OUT;
        int gg = r >> 3, j = r & 7;
        int koct = gg >> 5, i = gg & 31, k = koct * 8 + j;
        v = 0.f;
        if (i < 4)
            v = (k < 128) ? Wl[fmap(k) * 4 + i]
              : (k < 224) ? Wl[k * 4 + i]
              : (k == 224) ? bl[i] : 0.f;
    }
    img[idx] = b16rne(v);
}

// ---------------------------------------------------------------------------
// Main kernel helpers
// ---------------------------------------------------------------------------
__device__ inline f32x16 MF32(bf16x8 a, bf16x8 b, f32x16 c) {
    return __builtin_amdgcn_mfma_f32_32x32x16_bf16(a, b, c, 0, 0, 0);
}
__device__ inline bf16x8 fr4(const u32 (&p)[4]) {
    union { u32 u[4]; bf16x8 v; } x;
    x.u[0] = p[0]; x.u[1] = p[1]; x.u[2] = p[2]; x.u[3] = p[3];
    return x.v;
}
__device__ inline bf16x8 frCB(u32 c0) {
    union { u32 u[4]; bf16x8 v; } x;
    x.u[0] = c0; x.u[1] = 0; x.u[2] = 0; x.u[3] = 0;
    return x.v;
}
__device__ inline bf16x8 ldA(const u16* base, int gi) {   // ds_read_b128
    union { uint4 q; bf16x8 v; } x;
    x.q = *(const uint4*)(base + (gi << 3));
    return x.v;
}
__device__ inline u32 pkbf(float a, float b) {            // a->low, b->high
    u32 ua = __builtin_bit_cast(u32, a) + 0x8000u;
    u32 ub = __builtin_bit_cast(u32, b) + 0x8000u;
    return __builtin_amdgcn_perm(ub, ua, 0x07060302u);
}
// async global->LDS stage, 16B/lane, 1KB chunks round-robined over 4 waves
__device__ inline void stageA(const u16* gsrc, u16* ldst, int bytes, int wave, int lane) {
    const char* gs = (const char*)gsrc + lane * 16;
    char* ls = (char*)ldst;
    for (int c = wave * 1024; c < bytes; c += 4096)
        __builtin_amdgcn_global_load_lds(
            (const __attribute__((address_space(1))) void*)(gs + c),
            (__attribute__((address_space(3))) void*)(ls + c), 16, 0, 0);
}
__device__ inline void zeroacc(f32x16 (&acc)[4][2]) {
#pragma unroll
    for (int t = 0; t < 4; t++)
#pragma unroll
        for (int n = 0; n < 2; n++)
#pragma unroll
            for (int r = 0; r < 16; r++) acc[t][n][r] = 0.f;
}
// ReLU + pack accumulators into next-layer B fragments (in-register handoff)
__device__ inline void buildH(const f32x16 (&acc)[4][2], u32 (&H)[2][8][4]) {
#pragma unroll
    for (int n = 0; n < 2; n++)
#pragma unroll
        for (int s = 0; s < 8; s++) {
            const int t = s >> 1, rb = (s & 1) * 8;
#pragma unroll
            for (int q = 0; q < 4; q++)
                H[n][s][q] = pkbf(fmaxf(acc[t][n][rb + 2 * q], 0.f),
                                  fmaxf(acc[t][n][rb + 2 * q + 1], 0.f));
        }
}

// counted vmcnt + raw barrier (T3/T4): staged loads stay in flight across
// the barrier; sched_barrier(0) pins ds_reads after the rendezvous.
#define WAITV(N) asm volatile("s_waitcnt vmcnt(" #N ")" ::: "memory")
#define BAR() do { __builtin_amdgcn_s_barrier(); __builtin_amdgcn_sched_barrier(0); } while (0)

// one global s-step: 4 m-tiles x 2 n-tiles = 8 MFMA, A from LDS granule
__device__ inline void mmRow(const u16* A, int h, int m32, int s,
                             bf16x8 B0, bf16x8 B1, f32x16 (&acc)[4][2]) {
#pragma unroll
    for (int t = 0; t < 4; t++) {
        bf16x8 a = ldA(A, (2 * s + h) * 128 + t * 32 + m32);
        acc[t][0] = MF32(a, B0, acc[t][0]);
        acc[t][1] = MF32(a, B1, acc[t][1]);
    }
}

// --- per-granule compute phases (5 s-steps = 40 MFMA each, except cL0b) ---
// hidden G0: s 0..4 -> H[0..4]
__device__ inline void cH04(const u16* A, int h, int m32, f32x16 (&acc)[4][2],
                            const u32 (&H)[2][8][4]) {
    __builtin_amdgcn_s_setprio(1);
#pragma unroll
    for (int s = 0; s < 5; s++)
        mmRow(A, h, m32, s, fr4(H[0][s]), fr4(H[1][s]), acc);
    __builtin_amdgcn_s_setprio(0);
}
// hidden G1: s 5..9 -> H[5..7], E[c0][t0], E[c0][t1]
__device__ inline void cH57E0(const u16* A, int h, int m32, f32x16 (&acc)[4][2],
                              const u32 (&H)[2][8][4], const u32 (&E)[2][3][2][4]) {
    __builtin_amdgcn_s_setprio(1);
    mmRow(A, h, m32, 0, fr4(H[0][5]), fr4(H[1][5]), acc);
    mmRow(A, h, m32, 1, fr4(H[0][6]), fr4(H[1][6]), acc);
    mmRow(A, h, m32, 2, fr4(H[0][7]), fr4(H[1][7]), acc);
    mmRow(A, h, m32, 3, fr4(E[0][0][0]), fr4(E[1][0][0]), acc);
    mmRow(A, h, m32, 4, fr4(E[0][0][1]), fr4(E[1][0][1]), acc);
    __builtin_amdgcn_s_setprio(0);
}
// hidden G2: s 10..14 -> E[c1][*], E[c2][*], bias
__device__ inline void cE12b(const u16* A, int h, int m32, f32x16 (&acc)[4][2],
                             const u32 (&E)[2][3][2][4], u32 CB0) {
    __builtin_amdgcn_s_setprio(1);
    mmRow(A, h, m32, 0, fr4(E[0][1][0]), fr4(E[1][1][0]), acc);
    mmRow(A, h, m32, 1, fr4(E[0][1][1]), fr4(E[1][1][1]), acc);
    mmRow(A, h, m32, 2, fr4(E[0][2][0]), fr4(E[1][2][0]), acc);
    mmRow(A, h, m32, 3, fr4(E[0][2][1]), fr4(E[1][2][1]), acc);
    mmRow(A, h, m32, 4, frCB(CB0), frCB(CB0), acc);
    __builtin_amdgcn_s_setprio(0);
}
// L0 g0: s 0..4 -> E[c0][*], E[c1][*], E[c2][t0]
__device__ inline void cL0a(const u16* A, int h, int m32, f32x16 (&acc)[4][2],
                            const u32 (&E)[2][3][2][4]) {
    __builtin_amdgcn_s_setprio(1);
#pragma unroll
    for (int s = 0; s < 5; s++)
        mmRow(A, h, m32, s, fr4(E[0][s >> 1][s & 1]), fr4(E[1][s >> 1][s & 1]), acc);
    __builtin_amdgcn_s_setprio(0);
}
// L0 g1: s 5..6 -> E[c2][t1], bias
__device__ inline void cL0b(const u16* A, int h, int m32, f32x16 (&acc)[4][2],
                            const u32 (&E)[2][3][2][4], u32 CB0) {
    __builtin_amdgcn_s_setprio(1);
    mmRow(A, h, m32, 0, fr4(E[0][2][1]), fr4(E[1][2][1]), acc);
    mmRow(A, h, m32, 1, frCB(CB0), frCB(CB0), acc);
    __builtin_amdgcn_s_setprio(0);
}

// ---------------------------------------------------------------------------
// Main fused-MLP kernel.  Block = 256 threads = 4 waves, 256 points/block.
// Wave: 64 points (2 n-tiles of 32), all 128 features (4 m-tiles of 32).
// Weights stream through a 3-slab x 20KB LDS ring with depth-2 prefetch:
// phase i stages granule i+2, computes granule i, waits counted vmcnt
// (just-issued chunks stay in flight across the barrier), raw s_barrier.
// Granules/layer = 3 (kocts 0..9 / 10..19 / 20..29) -> slab indices are
// compile-time stable in the rolled layer loop.
// ---------------------------------------------------------------------------
__global__ __launch_bounds__(256, 2) void nf_main(const float* __restrict__ qp,
                                                  const u16* __restrict__ img,
                                                  float* __restrict__ out) {
    __shared__ alignas(16) u16 lds[3][10240];              // 61440 B
    const int tid = threadIdx.x, wave = tid >> 6, lane = tid & 63;
    const int m32 = lane & 31, h = lane >> 5;
    const int pbase = blockIdx.x * 256 + wave * 64;

    stageA(img, &lds[0][0], 20480, wave, lane);            // g0: L0 kocts 0..9  (5 ch/wave)
    stageA(img + 10240, &lds[1][0], 8192, wave, lane);     // g1: L0 kocts 10..13 (2 ch/wave)

    // ---- encoding fragments, computed ONCE, kept in registers ----
    u32 E[2][3][2][4];
    const float sc0 = h ? 128.0f : 0.5f;                   // 2^(8h-1) revolutions
#pragma unroll
    for (int n = 0; n < 2; n++)
#pragma unroll
        for (int c = 0; c < 3; c++) {
            float r = qp[(pbase + n * 32 + m32) * 3 + c] * sc0;
            float sn[8], cs[8];
#pragma unroll
            for (int t = 0; t < 8; t++) {
                float fr = __builtin_amdgcn_fractf(r);
                sn[t] = __builtin_amdgcn_sinf(fr);
                cs[t] = __builtin_amdgcn_cosf(fr);
                r = r * 2.0f;
            }
#pragma unroll
            for (int q = 0; q < 4; q++) {
                E[n][c][0][q] = pkbf(sn[2 * q], sn[2 * q + 1]);
                E[n][c][1][q] = pkbf(cs[2 * q], cs[2 * q + 1]);
            }
        }
    const u32 CB0 = (h == 0) ? 0x00003F80u : 0u;           // bf16(1.0) at j=0,h=0

    f32x16 acc[4][2];
    u32 H[2][8][4];
    zeroacc(acc);

    WAITV(2); BAR();                                       // g0 certified (g1's 2 in flight)
    stageA(img + IMG_H(1), &lds[2][0], 20480, wave, lane); // g2: H1 G0
    cL0a(&lds[0][0], h, m32, acc, E);
    WAITV(5); BAR();                                       // g1 certified (g2's 5 in flight)
    stageA(img + IMG_H(1) + 10240, &lds[0][0], 20480, wave, lane); // g3: H1 G1
    cL0b(&lds[1][0], h, m32, acc, E, CB0);
    buildH(acc, H);
    WAITV(5); BAR();                                       // g2 certified (g3's 5 in flight)

#pragma unroll 1
    for (int l = 1; l < 8; l++) {
        const int base = IMG_H(l);
        // P0: G0 (kocts 0..9) in lds[2]
        stageA(img + base + 20480, &lds[1][0], 20480, wave, lane);  // G2
        zeroacc(acc);
        cH04(&lds[2][0], h, m32, acc, H);
        WAITV(5); BAR();                                   // G1 certified
        // P1: G1 (kocts 10..19) in lds[0]
        const u16* nsrc = (l < 7) ? (img + IMG_H(l + 1)) : (img + IMG_OUT);
        stageA(nsrc, &lds[2][0], (l < 7) ? 20480 : 15360, wave, lane); // next G0 / Out
        cH57E0(&lds[0][0], h, m32, acc, H, E);
        if (l < 7) { WAITV(5); } else { WAITV(3); }        // G2 certified (Out: min chunks/wave=3)
        BAR();
        // P2: G2 (kocts 20..29) in lds[1]
        if (l < 7)
            stageA(img + IMG_H(l + 1) + 10240, &lds[0][0], 20480, wave, lane); // next G1
        cE12b(&lds[1][0], h, m32, acc, E, CB0);
        buildH(acc, H);
        if (l < 7) { WAITV(5); } else { WAITV(0); }        // next G0 / Out certified
        BAR();
    }

    // ---- output layer: one 32-row m-tile (rows 0..3 real), K=240, lds[2] ----
    f32x16 o0, o1;
#pragma unroll
    for (int r = 0; r < 16; r++) { o0[r] = 0.f; o1[r] = 0.f; }
    __builtin_amdgcn_s_setprio(1);
#pragma unroll
    for (int s = 0; s < 15; s++) {
        bf16x8 B0, B1;
        if (s < 8)       { B0 = fr4(H[0][s]); B1 = fr4(H[1][s]); }
        else if (s < 14) { B0 = fr4(E[0][(s - 8) >> 1][(s - 8) & 1]);
                           B1 = fr4(E[1][(s - 8) >> 1][(s - 8) & 1]); }
        else             { B0 = frCB(CB0); B1 = B0; }
        bf16x8 a = ldA(&lds[2][0], (2 * s + h) * 32 + m32);
        o0 = MF32(a, B0, o0);
        o1 = MF32(a, B1, o1);
    }
    __builtin_amdgcn_s_setprio(0);
    if (h == 0) {   // rows 0..3 live in regs 0..3 of the h=0 half
        f32x4 w0 = {o0[0], o0[1], o0[2], o0[3]};
        f32x4 w1 = {o1[0], o1[1], o1[2], o1[3]};
        *(f32x4*)(out + 4 * (pbase + m32)) = w0;
        *(f32x4*)(out + 4 * (pbase + 32 + m32)) = w1;
    }
}

// ---------------------------------------------------------------------------
extern "C" void kernel_launch(void* const* d_in, const int* in_sizes, int n_in,
                              void* d_out, int out_size, void* d_ws, size_t ws_size,
                              hipStream_t stream) {
    const float* qp = (const float*)d_in[0];
    const float* W0 = (const float*)d_in[1];
    const float* b0 = (const float*)d_in[2];
    const float* Wh = (const float*)d_in[3];
    const float* bh = (const float*)d_in[4];
    const float* Wl = (const float*)d_in[5];
    const float* bl = (const float*)d_in[6];
    float* out = (float*)d_out;
    u16* img = (u16*)d_ws;   // 474,112 B needed

    nf_prep<<<926, 256, 0, stream>>>(W0, b0, Wh, bh, Wl, bl, img);
    nf_main<<<2048, 256, 0, stream>>>(qp, img, out);
}